// Round 4
// baseline (34247.897 us; speedup 1.0000x reference)
//
#include <hip/hip_runtime.h>

// 2-layer tanh RNN, B=64, S=2048, D=HID=512.
// Round 11: fast transport v3 — plain coalesced loads on never-reused
// addresses.
// Geometry (r8-r10): block = 128 thr = wave0 (L0,jg) + wave1 (L1,jg);
// blockIdx = jg*8 + bg, residues 4..7 exit => the 64 waves of a batch-group
// share one XCD.
//
// r10 post-mortem: PASS @29ms, FETCH 2.07GB->132MB => probe VALIDATED and
// fast path was adopted; placement + (write-through store, vmcnt ack, TCC
// visibility) are hardware-proven. But atomic-RMW data reads de-coalesce a
// wave's 1KB read into 64 serialized TCC atomics => 14us/step, 2x WORSE
// than agent scope. Flags keep atomic-RMW polls (tiny, proven); data moves
// to plain loads made provably fresh by address rotation:
//   h slots rotate through DEPTH=64 buffers/layer (8MB). A consumer CU
//   re-reads an address only after 64 steps ~ 5MB streamed through its
//   32KB L1 => retention probability <= e^-160 under any replacement
//   policy; compulsory L1 miss => served by the XCD L2 (fresh, r10-proven).
// Side effect: L0->L1 WAR distance grows 3 -> 63, decoupling the layers.
// PROBE extended to 80 steps so validation covers the first slot-reuse
// window (t=64..79). Verdict!=0 => slow path + 2ms telemetry stall (~18ms
// PASS, diagnosable). ws_size checked (needs ~9.5MB); else all-slow.

#define SEQ    2048
#define PROBE  80
#define DEPTH  64
#define DMASK  (DEPTH - 1)

typedef _Float16 half8 __attribute__((ext_vector_type(8)));
typedef float floatx4 __attribute__((ext_vector_type(4)));
typedef unsigned long long u64;

__device__ inline half8 cvt8(const float* p) {
    float4 f0 = ((const float4*)p)[0];
    float4 f1 = ((const float4*)p)[1];
    half8 h;
    h[0]=(_Float16)f0.x; h[1]=(_Float16)f0.y; h[2]=(_Float16)f0.z; h[3]=(_Float16)f0.w;
    h[4]=(_Float16)f1.x; h[5]=(_Float16)f1.y; h[6]=(_Float16)f1.z; h[7]=(_Float16)f1.w;
    return h;
}

// ===== agent-scope (MALL) primitives — round-7 proven slow/truth path =====
__device__ inline u64 ld8_l3(const void* p) {
    return __hip_atomic_load((const u64*)p, __ATOMIC_RELAXED, __HIP_MEMORY_SCOPE_AGENT);
}
__device__ inline half8 ldfrag_l3(const _Float16* p) {
    union { u64 d[2]; half8 h; } u;
    u.d[0] = ld8_l3(p); u.d[1] = ld8_l3(p + 4);
    return u.h;
}
__device__ inline int ldflag_l3(const int* p) {
    return __hip_atomic_load(p, __ATOMIC_RELAXED, __HIP_MEMORY_SCOPE_AGENT);
}
__device__ inline void st2_l3(_Float16* p, unsigned short v) {
    __hip_atomic_store((unsigned short*)p, v, __ATOMIC_RELAXED, __HIP_MEMORY_SCOPE_AGENT);
}
__device__ inline void stflag_l3(int* p, int v) {
    __hip_atomic_store(p, v, __ATOMIC_RELAXED, __HIP_MEMORY_SCOPE_AGENT);
}

// ===== XCD-local fast primitives =====
// Flags: atomic fetch_add(p,0) executes at the TCC — L1-bypassing read
// (r10-proven correct). Data: PLAIN coalesced loads; freshness guaranteed
// by never-reused addresses (rotation depth 64), not by cache bypass.
__device__ inline int ldflag_l2(int* p) {
    return __hip_atomic_fetch_add(p, 0, __ATOMIC_RELAXED,
                                  __HIP_MEMORY_SCOPE_WORKGROUP);
}
__device__ inline void stflag_l2(int* p, int v) {
    __hip_atomic_store(p, v, __ATOMIC_RELAXED, __HIP_MEMORY_SCOPE_WORKGROUP);
}
__device__ inline half8 ldfrag_fast(const _Float16* p) {
    return *reinterpret_cast<const half8*>(p);   // global_load_dwordx4
}

__device__ inline int neq8(half8 a, half8 b) {
    union { half8 h; u64 d[2]; } ua, ub; ua.h = a; ub.h = b;
    return (ua.d[0] != ub.d[0]) | (ua.d[1] != ub.d[1]);
}

#define MFMA(a, b, c) __builtin_amdgcn_mfma_f32_16x16x32_f16((a), (b), (c), 0, 0, 0)

// ===== main loop, M = 0 slow (agent, 4 slots) / 1 fast (L2, 64 slots) =====
template<int M>
__device__ __forceinline__ void run_range(
    const int t0, const int lane, const int L, const int bg, const int jg,
    const int* __restrict__ src, const float* __restrict__ embed,
    const half8* bw, const float bias, float* __restrict__ out,
    _Float16* h0s, _Float16* h1s, int* flg)
{
    const int q    = lane >> 4;
    const int rr   = lane & 15;
    const int col  = jg * 16 + rr;
    const int arow = bg * 16 + rr;
    const int lf   = lane >> 5;
    const int SLOTM = (M == 0) ? 3 : DMASK;        // slot index mask
    const int WAR   = (M == 0) ? 3 : (DEPTH - 1);  // L0 back-pressure distance
    int degraded = 0;      // sticky: first fast-poll timeout shrinks bounds

    for (int t = t0; t < SEQ; ++t) {
        floatx4 acc0 = {0.f,0.f,0.f,0.f}, acc1 = {0.f,0.f,0.f,0.f};

        if (L == 0) {
            const int erow = src[arow * SEQ + t];
            const float* eb = embed + (size_t)erow * 512 + q * 8;
            half8 ax[16];
            #pragma unroll
            for (int u = 0; u < 16; ++u) ax[u] = cvt8(eb + u * 32);
            #pragma unroll
            for (int u = 0; u < 16; ++u) {
                if (u & 1) acc1 = MFMA(ax[u], bw[u], acc1);
                else       acc0 = MFMA(ax[u], bw[u], acc0);
            }
            const int tgt = (lf == 0) ? t : (t - WAR);
            {
                const long bound = (M == 0) ? (1L << 26)
                                            : (degraded ? 64 : (1L << 17));
                bool ok = false;
                for (long it = 0; it < bound; ++it) {
                    int v = (M == 0) ? ldflag_l3(&flg[lane]) : ldflag_l2(&flg[lane]);
                    if (__ballot(v >= tgt) == ~0ull) { ok = true; break; }
                    __builtin_amdgcn_s_sleep(1);
                }
                if (!ok) degraded = 1;
            }
            __atomic_signal_fence(__ATOMIC_SEQ_CST);
            if (t > 0) {
                const _Float16* hb = h0s + ((t - 1) & SLOTM) * (64 * 512)
                                   + arow * 512 + q * 8;
                half8 ah[16];
                #pragma unroll
                for (int u = 0; u < 16; ++u)
                    ah[u] = (M == 0) ? ldfrag_l3(hb + u * 32)
                                     : ldfrag_fast(hb + u * 32);
                #pragma unroll
                for (int u = 0; u < 16; ++u) {
                    if (u & 1) acc1 = MFMA(ah[u], bw[16 + u], acc1);
                    else       acc0 = MFMA(ah[u], bw[16 + u], acc0);
                }
            }
        } else {
            const int tgt = (lf == 0) ? (t + 1) : t;
            {
                const long bound = (M == 0) ? (1L << 26)
                                            : (degraded ? 64 : (1L << 17));
                bool ok = false;
                for (long it = 0; it < bound; ++it) {
                    int v = (M == 0) ? ldflag_l3(&flg[lane]) : ldflag_l2(&flg[lane]);
                    if (__ballot(v >= tgt) == ~0ull) { ok = true; break; }
                    __builtin_amdgcn_s_sleep(1);
                }
                if (!ok) degraded = 1;
            }
            __atomic_signal_fence(__ATOMIC_SEQ_CST);
            {
                const _Float16* xa = h0s + (t & SLOTM) * (64 * 512)
                                   + arow * 512 + q * 8;
                half8 ax[16];
                #pragma unroll
                for (int u = 0; u < 16; ++u)
                    ax[u] = (M == 0) ? ldfrag_l3(xa + u * 32)
                                     : ldfrag_fast(xa + u * 32);
                #pragma unroll
                for (int u = 0; u < 16; ++u) {
                    if (u & 1) acc1 = MFMA(ax[u], bw[u], acc1);
                    else       acc0 = MFMA(ax[u], bw[u], acc0);
                }
            }
            if (t > 0) {
                const _Float16* hb = h1s + ((t - 1) & SLOTM) * (64 * 512)
                                   + arow * 512 + q * 8;
                half8 ah[16];
                #pragma unroll
                for (int u = 0; u < 16; ++u)
                    ah[u] = (M == 0) ? ldfrag_l3(hb + u * 32)
                                     : ldfrag_fast(hb + u * 32);
                #pragma unroll
                for (int u = 0; u < 16; ++u) {
                    if (u & 1) acc1 = MFMA(ah[u], bw[16 + u], acc1);
                    else       acc0 = MFMA(ah[u], bw[16 + u], acc0);
                }
            }
        }

        float hv[4];
        #pragma unroll
        for (int r = 0; r < 4; ++r)
            hv[r] = tanhf(acc0[r] + acc1[r] + bias);

        if (t == SEQ - 1) {
            #pragma unroll
            for (int r = 0; r < 4; ++r)
                out[(size_t)L * 64 * 512 + (size_t)(bg * 16 + q * 4 + r) * 512 + col]
                    = hv[r];
        }

        {
            _Float16* hw = ((L == 0) ? h0s : h1s) + (t & SLOTM) * (64 * 512)
                         + (size_t)(bg * 16) * 512 + col;
            #pragma unroll
            for (int r = 0; r < 4; ++r) {
                union { _Float16 f; unsigned short u; } cv;
                cv.f = (_Float16)hv[r];
                if (M == 0) st2_l3(hw + (q * 4 + r) * 512, cv.u);
                else        hw[(q * 4 + r) * 512] = cv.f;   // plain write-through
            }
        }
        __atomic_signal_fence(__ATOMIC_SEQ_CST);
        __builtin_amdgcn_s_waitcnt(0);     // stores ACKed at L2 (fast) / MALL (slow)
        __atomic_signal_fence(__ATOMIC_SEQ_CST);
        if (lane == 0) {
            if (M == 0) stflag_l3(&flg[L * 32 + jg], t + 1);
            else        stflag_l2(&flg[L * 32 + jg], t + 1);
        }
    }
}

// ===== probe: steps 0..PROBE-1 on slow protocol, mirroring + validating =====
// Mirror uses the FULL fast mechanism (rotating slots, plain stores/loads,
// TCC-atomic flags); PROBE=80 > DEPTH so the first slot-reuse window
// (t=64..79) is validated bit-exact before adoption.
__device__ __forceinline__ void run_probe(
    const int lane, const int L, const int bg, const int jg,
    const int* __restrict__ src, const float* __restrict__ embed,
    const half8* bw, const float bias,
    _Float16* h0s, _Float16* h1s, int* flg,       // slow (truth), 4 slots
    _Float16* f0s, _Float16* f1s, int* flgF,      // fast mirrors, DEPTH slots
    int* verdict)
{
    const int q    = lane >> 4;
    const int rr   = lane & 15;
    const int col  = jg * 16 + rr;
    const int arow = bg * 16 + rr;
    const int lf   = lane >> 5;
    int bad = 0;

    for (int t = 0; t < PROBE; ++t) {
        floatx4 acc0 = {0.f,0.f,0.f,0.f}, acc1 = {0.f,0.f,0.f,0.f};
        const int tgt = (L == 0) ? ((lf == 0) ? t : (t - 3))
                                 : ((lf == 0) ? (t + 1) : t);

        if (L == 0) {
            const int erow = src[arow * SEQ + t];
            const float* eb = embed + (size_t)erow * 512 + q * 8;
            half8 ax[16];
            #pragma unroll
            for (int u = 0; u < 16; ++u) ax[u] = cvt8(eb + u * 32);
            #pragma unroll
            for (int u = 0; u < 16; ++u) {
                if (u & 1) acc1 = MFMA(ax[u], bw[u], acc1);
                else       acc0 = MFMA(ax[u], bw[u], acc0);
            }
        }

        // slow poll (ground-truth ordering)
        for (long it = 0; it < (1L << 26); ++it) {
            int v = ldflag_l3(&flg[lane]);
            if (__ballot(v >= tgt) == ~0ull) break;
            __builtin_amdgcn_s_sleep(1);
        }
        __atomic_signal_fence(__ATOMIC_SEQ_CST);

        // fast-flag visibility check (bounded; failure = defect, not hang)
        {
            bool ok = false;
            for (long it = 0; it < 256; ++it) {
                int v = ldflag_l2(&flgF[lane]);
                if (__ballot(v >= tgt) == ~0ull) { ok = true; break; }
                __builtin_amdgcn_s_sleep(1);
            }
            if (!ok) bad = 1;
        }

        if (L == 0) {
            if (t > 0) {
                const size_t offS = ((t - 1) & 3) * (64 * 512) + arow * 512 + q * 8;
                const size_t offF = ((t - 1) & DMASK) * (64 * 512) + arow * 512 + q * 8;
                half8 ah[16];
                #pragma unroll
                for (int u = 0; u < 16; ++u) {
                    ah[u] = ldfrag_l3(h0s + offS + u * 32);
                    half8 fh = ldfrag_fast(f0s + offF + u * 32);
                    bad |= neq8(ah[u], fh);
                }
                #pragma unroll
                for (int u = 0; u < 16; ++u) {
                    if (u & 1) acc1 = MFMA(ah[u], bw[16 + u], acc1);
                    else       acc0 = MFMA(ah[u], bw[16 + u], acc0);
                }
            }
        } else {
            {
                const size_t offS = (t & 3) * (64 * 512) + arow * 512 + q * 8;
                const size_t offF = (t & DMASK) * (64 * 512) + arow * 512 + q * 8;
                half8 ax[16];
                #pragma unroll
                for (int u = 0; u < 16; ++u) {
                    ax[u] = ldfrag_l3(h0s + offS + u * 32);
                    half8 fh = ldfrag_fast(f0s + offF + u * 32);
                    bad |= neq8(ax[u], fh);
                }
                #pragma unroll
                for (int u = 0; u < 16; ++u) {
                    if (u & 1) acc1 = MFMA(ax[u], bw[u], acc1);
                    else       acc0 = MFMA(ax[u], bw[u], acc0);
                }
            }
            if (t > 0) {
                const size_t offS = ((t - 1) & 3) * (64 * 512) + arow * 512 + q * 8;
                const size_t offF = ((t - 1) & DMASK) * (64 * 512) + arow * 512 + q * 8;
                half8 ah[16];
                #pragma unroll
                for (int u = 0; u < 16; ++u) {
                    ah[u] = ldfrag_l3(h1s + offS + u * 32);
                    half8 fh = ldfrag_fast(f1s + offF + u * 32);
                    bad |= neq8(ah[u], fh);
                }
                #pragma unroll
                for (int u = 0; u < 16; ++u) {
                    if (u & 1) acc1 = MFMA(ah[u], bw[16 + u], acc1);
                    else       acc0 = MFMA(ah[u], bw[16 + u], acc0);
                }
            }
        }

        float hv[4];
        #pragma unroll
        for (int r = 0; r < 4; ++r)
            hv[r] = tanhf(acc0[r] + acc1[r] + bias);

        {
            const size_t offS = (t & 3) * (64 * 512) + (size_t)(bg * 16) * 512 + col;
            const size_t offF = (t & DMASK) * (64 * 512) + (size_t)(bg * 16) * 512 + col;
            _Float16* hwS = ((L == 0) ? h0s : h1s) + offS;
            _Float16* hwF = ((L == 0) ? f0s : f1s) + offF;
            #pragma unroll
            for (int r = 0; r < 4; ++r) {
                union { _Float16 f; unsigned short u; } cv;
                cv.f = (_Float16)hv[r];
                st2_l3(hwS + (q * 4 + r) * 512, cv.u);
                hwF[(q * 4 + r) * 512] = cv.f;     // plain write-through
            }
        }
        // fold wave verdict into group verdict before the last stamp
        if (t == PROBE - 1) {
            const int anybad = (__ballot(bad) != 0ull) ? 1 : 0;
            if (lane == 0 && anybad)
                __hip_atomic_fetch_or(verdict, 1, __ATOMIC_RELAXED,
                                      __HIP_MEMORY_SCOPE_AGENT);
        }
        __atomic_signal_fence(__ATOMIC_SEQ_CST);
        __builtin_amdgcn_s_waitcnt(0);   // h (both), verdict drained
        __atomic_signal_fence(__ATOMIC_SEQ_CST);
        if (lane == 0) {
            stflag_l2(&flgF[L * 32 + jg], t + 1);
            stflag_l3(&flg[L * 32 + jg], t + 1);
        }
    }
}

__global__ __launch_bounds__(128, 1)
void rnn_persist(const int* __restrict__ src, const float* __restrict__ embed,
                 const float* __restrict__ W_ih, const float* __restrict__ W_hh,
                 const float* __restrict__ b_ih, const float* __restrict__ b_hh,
                 float* __restrict__ out, _Float16* hS, _Float16* hF,
                 int* flagsS, int* flagsF, int* verdict, int fastEnable)
{
    const int b = blockIdx.x;
    if ((b & 7) >= 4) return;            // residues 4..7: padding blocks, exit
    const int bg  = b & 7;               // 0..3; XCD = b % 8 under round-robin
    const int jg  = b >> 3;
    const int tid = threadIdx.x;
    const int lane = tid & 63;
    const int L    = tid >> 6;           // wave0 = layer 0, wave1 = layer 1

    // persistent weights: 16 cols x K=1024, f16, 128 VGPRs
    const int q = lane >> 4, rr = lane & 15;
    const int col = jg * 16 + rr;
    half8 bw[32];
    {
        const float* Wi = W_ih + ((size_t)L * 512 + col) * 512;
        const float* Wh = W_hh + ((size_t)L * 512 + col) * 512;
        #pragma unroll
        for (int u = 0; u < 16; ++u) bw[u]      = cvt8(Wi + u * 32 + q * 8);
        #pragma unroll
        for (int u = 0; u < 16; ++u) bw[16 + u] = cvt8(Wh + u * 32 + q * 8);
    }
    const float bias = b_ih[L * 512 + col] + b_hh[L * 512 + col];

    _Float16* h0sS = hS;  _Float16* h1sS = hS + 4 * 64 * 512;
    _Float16* h0sF = hF;  _Float16* h1sF = hF + DEPTH * 64 * 512;
    int* flgS = flagsS + bg * 64;
    int* flgF = flagsF + bg * 64;

    if (!fastEnable) {   // workspace too small for rotation: proven slow path
        run_range<0>(0, lane, L, bg, jg, src, embed, bw, bias, out,
                     h0sS, h1sS, flgS);
        return;
    }

    run_probe(lane, L, bg, jg, src, embed, bw, bias,
              h0sS, h1sS, flgS, h0sF, h1sF, flgF, &verdict[bg]);

    // group barrier: all 64 stamps >= PROBE  =>  all verdict ORs are at MALL
    for (long it = 0; it < (1L << 26); ++it) {
        int v = ldflag_l3(&flgS[lane]);
        if (__ballot(v >= PROBE) == ~0ull) break;
        __builtin_amdgcn_s_sleep(1);
    }
    __atomic_signal_fence(__ATOMIC_SEQ_CST);
    const int vd = __hip_atomic_load(&verdict[bg], __ATOMIC_RELAXED,
                                     __HIP_MEMORY_SCOPE_AGENT);

    if (vd == 0) {
        run_range<1>(PROBE, lane, L, bg, jg, src, embed, bw, bias, out,
                     h0sF, h1sF, flgF);
    } else {
        // telemetry stall ~2 ms: a slow verdict is readable from dur_us
        for (int i = 0; i < 600; ++i) __builtin_amdgcn_s_sleep(125);
        run_range<0>(PROBE, lane, L, bg, jg, src, embed, bw, bias, out,
                     h0sS, h1sS, flgS);
    }
}

extern "C" void kernel_launch(void* const* d_in, const int* in_sizes, int n_in,
                              void* d_out, int out_size, void* d_ws, size_t ws_size,
                              hipStream_t stream) {
    const int*   src   = (const int*)  d_in[0];
    const float* embed = (const float*)d_in[1];
    const float* W_ih  = (const float*)d_in[2];
    const float* W_hh  = (const float*)d_in[3];
    const float* b_ih  = (const float*)d_in[4];
    const float* b_hh  = (const float*)d_in[5];
    float* out = (float*)d_out;

    int*      flagsS  = (int*)d_ws;                  // bytes [0,1024)
    int*      flagsF  = (int*)d_ws + 256;            // bytes [1024,2048)
    int*      verdict = (int*)d_ws + 512;            // bytes [2048,2064)
    _Float16* hS = (_Float16*)((char*)d_ws + 16384);           // 512 KB slow h
    // fast h: 2 layers x DEPTH slots x 64x512 f16 = 8 MB at offset 1 MB
    const size_t need = (size_t)1048576 + (size_t)2 * DEPTH * 64 * 512 * 2 + 65536;
    const int fastEnable = (ws_size >= need) ? 1 : 0;
    _Float16* hF = fastEnable ? (_Float16*)((char*)d_ws + 1048576) : hS;

    // flags/verdict must start at 0 each launch (ws re-poisoned to 0xAA);
    // h slots need no init: t==0 skips all h-slot reads.
    hipMemsetAsync(d_ws, 0, 16384, stream);

    // 256 blocks x 128 threads; residues 0..3 (mod 8) active so each bg's 64
    // waves share one XCD. Co-residency by capacity: 256 blocks <= 256 CUs.
    rnn_persist<<<dim3(256), dim3(128), 0, stream>>>(
        src, embed, W_ih, W_hh, b_ih, b_hh, out, hS, hF,
        flagsS, flagsF, verdict, fastEnable);
}

// Round 6
// 23503.978 us; speedup vs baseline: 1.4571x; 1.4571x over previous
//
#include <hip/hip_runtime.h>

// 2-layer tanh RNN, B=64, S=2048, D=HID=512.
// Round 13: r11's PROVEN protocol with stamps spread to one line per wave.
// Geometry (r8+): block = 128 thr = wave0 (L0,jg) + wave1 (L1,jg);
// blockIdx = jg*8 + bg, residues 4..7 exit => 64 waves of a bg on one XCD.
//
// r12 post-mortem: counter sync was SUM-semantics, not MIN — waves skew,
// consumers read unwritten slots => FAIL (absmax 1.53). Also DEPTH=16
// weakened the L1-freshness-by-rotation argument (survival e^-15/line under
// random replacement => ~dozen stale reads/run). Both reverted.
// This round = r11's bit-exact-proven fast path (DEPTH=64 rotation, plain
// write-through stores + vmcnt ack, plain coalesced loads, per-wave stamps
// + 64-lane ballot MIN check) with ONE change: stamp ADDRESSES.
//   r11: 64 stamps packed in two 128B lines -> poll = 4096 same-line RMWs
//        per round ~ 6-12us (the real cost of r10/r11).
//   r13: stamp[wave] at its own 128B line (8KB/bg); consumer lane i polls
//        line i only -> 64 RMWs/line/round in parallel ~ 0.3-0.6us.
// Probe (24 steps, slow-truth mirror+compare) revalidates transport at the
// new addresses; verdict!=0 => slow path + 2ms telemetry stall (~18ms PASS).

#define SEQ    2048
#define PROBE  24
#define DEPTH  64
#define DMASK  (DEPTH - 1)
#define FSTR   32              // ints between fast stamps = 128 B

typedef _Float16 half8 __attribute__((ext_vector_type(8)));
typedef float floatx4 __attribute__((ext_vector_type(4)));
typedef unsigned long long u64;

__device__ inline half8 cvt8(const float* p) {
    float4 f0 = ((const float4*)p)[0];
    float4 f1 = ((const float4*)p)[1];
    half8 h;
    h[0]=(_Float16)f0.x; h[1]=(_Float16)f0.y; h[2]=(_Float16)f0.z; h[3]=(_Float16)f0.w;
    h[4]=(_Float16)f1.x; h[5]=(_Float16)f1.y; h[6]=(_Float16)f1.z; h[7]=(_Float16)f1.w;
    return h;
}

// ===== agent-scope (MALL) primitives — round-7 proven slow/truth path =====
__device__ inline u64 ld8_l3(const void* p) {
    return __hip_atomic_load((const u64*)p, __ATOMIC_RELAXED, __HIP_MEMORY_SCOPE_AGENT);
}
__device__ inline half8 ldfrag_l3(const _Float16* p) {
    union { u64 d[2]; half8 h; } u;
    u.d[0] = ld8_l3(p); u.d[1] = ld8_l3(p + 4);
    return u.h;
}
__device__ inline int ldflag_l3(const int* p) {
    return __hip_atomic_load(p, __ATOMIC_RELAXED, __HIP_MEMORY_SCOPE_AGENT);
}
__device__ inline void st2_l3(_Float16* p, unsigned short v) {
    __hip_atomic_store((unsigned short*)p, v, __ATOMIC_RELAXED, __HIP_MEMORY_SCOPE_AGENT);
}
__device__ inline void stflag_l3(int* p, int v) {
    __hip_atomic_store(p, v, __ATOMIC_RELAXED, __HIP_MEMORY_SCOPE_AGENT);
}

// ===== XCD-local fast primitives (r10/r11-proven) =====
// Stamp read: atomic fetch_add(0) executes at the TCC — L1-bypassing.
// Stamp write: workgroup-scope atomic store (executes at TCC).
// Data: PLAIN stores (write-through, vmcnt-acked) + PLAIN coalesced loads,
// freshness by DEPTH=64 rotation (r11-proven bit-exact over full run).
__device__ inline int ldstamp(int* p) {
    return __hip_atomic_fetch_add(p, 0, __ATOMIC_RELAXED,
                                  __HIP_MEMORY_SCOPE_WORKGROUP);
}
__device__ inline void ststamp(int* p, int v) {
    __hip_atomic_store(p, v, __ATOMIC_RELAXED, __HIP_MEMORY_SCOPE_WORKGROUP);
}
__device__ inline half8 ldfrag_fast(const _Float16* p) {
    return *reinterpret_cast<const half8*>(p);   // global_load_dwordx4
}

__device__ inline int neq8(half8 a, half8 b) {
    union { half8 h; u64 d[2]; } ua, ub; ua.h = a; ub.h = b;
    return (ua.d[0] != ub.d[0]) | (ua.d[1] != ub.d[1]);
}

#define MFMA(a, b, c) __builtin_amdgcn_mfma_f32_16x16x32_f16((a), (b), (c), 0, 0, 0)

// ===== slow path (agent scope, 4 slots, packed per-wave stamps) — proven =====
__device__ __forceinline__ void run_slow(
    const int t0, const int lane, const int L, const int bg, const int jg,
    const int* __restrict__ src, const float* __restrict__ embed,
    const half8* bw, const float bias, float* __restrict__ out,
    _Float16* h0s, _Float16* h1s, int* flg)
{
    const int q    = lane >> 4;
    const int rr   = lane & 15;
    const int col  = jg * 16 + rr;
    const int arow = bg * 16 + rr;
    const int lf   = lane >> 5;

    for (int t = t0; t < SEQ; ++t) {
        floatx4 acc0 = {0.f,0.f,0.f,0.f}, acc1 = {0.f,0.f,0.f,0.f};

        if (L == 0) {
            const int erow = src[arow * SEQ + t];
            const float* eb = embed + (size_t)erow * 512 + q * 8;
            half8 ax[16];
            #pragma unroll
            for (int u = 0; u < 16; ++u) ax[u] = cvt8(eb + u * 32);
            #pragma unroll
            for (int u = 0; u < 16; ++u) {
                if (u & 1) acc1 = MFMA(ax[u], bw[u], acc1);
                else       acc0 = MFMA(ax[u], bw[u], acc0);
            }
            const int tgt = (lf == 0) ? t : (t - 3);
            for (long it = 0; it < (1L << 26); ++it) {
                int v = ldflag_l3(&flg[lane]);
                if (__ballot(v >= tgt) == ~0ull) break;
                __builtin_amdgcn_s_sleep(1);
            }
            __atomic_signal_fence(__ATOMIC_SEQ_CST);
            if (t > 0) {
                const _Float16* hb = h0s + ((t - 1) & 3) * (64 * 512)
                                   + arow * 512 + q * 8;
                half8 ah[16];
                #pragma unroll
                for (int u = 0; u < 16; ++u) ah[u] = ldfrag_l3(hb + u * 32);
                #pragma unroll
                for (int u = 0; u < 16; ++u) {
                    if (u & 1) acc1 = MFMA(ah[u], bw[16 + u], acc1);
                    else       acc0 = MFMA(ah[u], bw[16 + u], acc0);
                }
            }
        } else {
            const int tgt = (lf == 0) ? (t + 1) : t;
            for (long it = 0; it < (1L << 26); ++it) {
                int v = ldflag_l3(&flg[lane]);
                if (__ballot(v >= tgt) == ~0ull) break;
                __builtin_amdgcn_s_sleep(1);
            }
            __atomic_signal_fence(__ATOMIC_SEQ_CST);
            {
                const _Float16* xa = h0s + (t & 3) * (64 * 512) + arow * 512 + q * 8;
                half8 ax[16];
                #pragma unroll
                for (int u = 0; u < 16; ++u) ax[u] = ldfrag_l3(xa + u * 32);
                #pragma unroll
                for (int u = 0; u < 16; ++u) {
                    if (u & 1) acc1 = MFMA(ax[u], bw[u], acc1);
                    else       acc0 = MFMA(ax[u], bw[u], acc0);
                }
            }
            if (t > 0) {
                const _Float16* hb = h1s + ((t - 1) & 3) * (64 * 512)
                                   + arow * 512 + q * 8;
                half8 ah[16];
                #pragma unroll
                for (int u = 0; u < 16; ++u) ah[u] = ldfrag_l3(hb + u * 32);
                #pragma unroll
                for (int u = 0; u < 16; ++u) {
                    if (u & 1) acc1 = MFMA(ah[u], bw[16 + u], acc1);
                    else       acc0 = MFMA(ah[u], bw[16 + u], acc0);
                }
            }
        }

        float hv[4];
        #pragma unroll
        for (int r = 0; r < 4; ++r)
            hv[r] = tanhf(acc0[r] + acc1[r] + bias);

        if (t == SEQ - 1) {
            #pragma unroll
            for (int r = 0; r < 4; ++r)
                out[(size_t)L * 64 * 512 + (size_t)(bg * 16 + q * 4 + r) * 512 + col]
                    = hv[r];
        }
        {
            _Float16* hw = ((L == 0) ? h0s : h1s) + (t & 3) * (64 * 512)
                         + (size_t)(bg * 16) * 512 + col;
            #pragma unroll
            for (int r = 0; r < 4; ++r) {
                union { _Float16 f; unsigned short u; } cv;
                cv.f = (_Float16)hv[r];
                st2_l3(hw + (q * 4 + r) * 512, cv.u);
            }
        }
        __atomic_signal_fence(__ATOMIC_SEQ_CST);
        __builtin_amdgcn_s_waitcnt(0);
        __atomic_signal_fence(__ATOMIC_SEQ_CST);
        if (lane == 0)
            stflag_l3(&flg[L * 32 + jg], t + 1);
    }
}

// ===== fast path: r11 protocol, stamps spread one line per wave =====
__device__ __forceinline__ void run_fast(
    const int t0, const int lane, const int L, const int bg, const int jg,
    const int* __restrict__ src, const float* __restrict__ embed,
    const half8* bw, const float bias, float* __restrict__ out,
    _Float16* h0f, _Float16* h1f, int* flgF)
{
    const int q    = lane >> 4;
    const int rr   = lane & 15;
    const int col  = jg * 16 + rr;
    const int arow = bg * 16 + rr;
    const int lf   = lane >> 5;
    int* pollp  = flgF + lane * FSTR;             // this lane's watched wave
    int* myst   = flgF + (L * 32 + jg) * FSTR;    // this wave's own stamp
    int degraded = 0;      // sticky: first poll timeout shrinks bounds

    for (int t = t0; t < SEQ; ++t) {
        floatx4 acc0 = {0.f,0.f,0.f,0.f}, acc1 = {0.f,0.f,0.f,0.f};
        int tgt;

        if (L == 0) {
            const int erow = src[arow * SEQ + t];
            const float* eb = embed + (size_t)erow * 512 + q * 8;
            half8 ax[16];
            #pragma unroll
            for (int u = 0; u < 16; ++u) ax[u] = cvt8(eb + u * 32);
            #pragma unroll
            for (int u = 0; u < 16; ++u) {
                if (u & 1) acc1 = MFMA(ax[u], bw[u], acc1);
                else       acc0 = MFMA(ax[u], bw[u], acc0);
            }
            tgt = (lf == 0) ? t : (t - DMASK);    // peers t-1 | cross-layer WAR
        } else {
            tgt = (lf == 0) ? (t + 1) : t;        // L0 done t | peers t-1
        }

        {   // MIN-semantics rendezvous: every lane checks its wave's stamp
            const long bound = degraded ? 64 : (1L << 13);
            bool ok = false;
            for (long it = 0; it < bound; ++it) {
                int v = ldstamp(pollp);
                if (__ballot(v >= tgt) == ~0ull) { ok = true; break; }
                __builtin_amdgcn_s_sleep(1);
            }
            if (!ok) degraded = 1;
        }
        __atomic_signal_fence(__ATOMIC_SEQ_CST);

        if (L == 0) {
            if (t > 0) {
                const _Float16* hb = h0f + ((t - 1) & DMASK) * (64 * 512)
                                   + arow * 512 + q * 8;
                half8 ah[16];
                #pragma unroll
                for (int u = 0; u < 16; ++u) ah[u] = ldfrag_fast(hb + u * 32);
                #pragma unroll
                for (int u = 0; u < 16; ++u) {
                    if (u & 1) acc1 = MFMA(ah[u], bw[16 + u], acc1);
                    else       acc0 = MFMA(ah[u], bw[16 + u], acc0);
                }
            }
        } else {
            {
                const _Float16* xa = h0f + (t & DMASK) * (64 * 512)
                                   + arow * 512 + q * 8;
                half8 ax[16];
                #pragma unroll
                for (int u = 0; u < 16; ++u) ax[u] = ldfrag_fast(xa + u * 32);
                #pragma unroll
                for (int u = 0; u < 16; ++u) {
                    if (u & 1) acc1 = MFMA(ax[u], bw[u], acc1);
                    else       acc0 = MFMA(ax[u], bw[u], acc0);
                }
            }
            if (t > 0) {
                const _Float16* hb = h1f + ((t - 1) & DMASK) * (64 * 512)
                                   + arow * 512 + q * 8;
                half8 ah[16];
                #pragma unroll
                for (int u = 0; u < 16; ++u) ah[u] = ldfrag_fast(hb + u * 32);
                #pragma unroll
                for (int u = 0; u < 16; ++u) {
                    if (u & 1) acc1 = MFMA(ah[u], bw[16 + u], acc1);
                    else       acc0 = MFMA(ah[u], bw[16 + u], acc0);
                }
            }
        }

        float hv[4];
        #pragma unroll
        for (int r = 0; r < 4; ++r)
            hv[r] = tanhf(acc0[r] + acc1[r] + bias);

        if (t == SEQ - 1) {
            #pragma unroll
            for (int r = 0; r < 4; ++r)
                out[(size_t)L * 64 * 512 + (size_t)(bg * 16 + q * 4 + r) * 512 + col]
                    = hv[r];
        }
        {
            _Float16* hw = ((L == 0) ? h0f : h1f) + (t & DMASK) * (64 * 512)
                         + (size_t)(bg * 16) * 512 + col;
            #pragma unroll
            for (int r = 0; r < 4; ++r) {
                union { _Float16 f; unsigned short u; } cv;
                cv.f = (_Float16)hv[r];
                hw[(q * 4 + r) * 512] = cv.f;    // plain write-through
            }
        }
        __atomic_signal_fence(__ATOMIC_SEQ_CST);
        __builtin_amdgcn_s_waitcnt(0);           // h stores ACKed at L2
        __atomic_signal_fence(__ATOMIC_SEQ_CST);
        if (lane == 0) ststamp(myst, t + 1);
    }
}

// ===== probe: steps 0..PROBE-1 on slow truth, mirroring + validating fast =====
__device__ __forceinline__ void run_probe(
    const int lane, const int L, const int bg, const int jg,
    const int* __restrict__ src, const float* __restrict__ embed,
    const half8* bw, const float bias,
    _Float16* h0s, _Float16* h1s, int* flg,       // slow (truth), 4 slots
    _Float16* f0s, _Float16* f1s, int* flgF,      // fast mirrors, DEPTH slots
    int* verdict)
{
    const int q    = lane >> 4;
    const int rr   = lane & 15;
    const int col  = jg * 16 + rr;
    const int arow = bg * 16 + rr;
    const int lf   = lane >> 5;
    int* pollpF = flgF + lane * FSTR;
    int* mystF  = flgF + (L * 32 + jg) * FSTR;
    int bad = 0;

    for (int t = 0; t < PROBE; ++t) {
        floatx4 acc0 = {0.f,0.f,0.f,0.f}, acc1 = {0.f,0.f,0.f,0.f};
        const int tgt  = (L == 0) ? ((lf == 0) ? t : (t - 3))
                                  : ((lf == 0) ? (t + 1) : t);
        const int tgtF = (L == 0) ? ((lf == 0) ? t : (t - DMASK))
                                  : ((lf == 0) ? (t + 1) : t);

        if (L == 0) {
            const int erow = src[arow * SEQ + t];
            const float* eb = embed + (size_t)erow * 512 + q * 8;
            half8 ax[16];
            #pragma unroll
            for (int u = 0; u < 16; ++u) ax[u] = cvt8(eb + u * 32);
            #pragma unroll
            for (int u = 0; u < 16; ++u) {
                if (u & 1) acc1 = MFMA(ax[u], bw[u], acc1);
                else       acc0 = MFMA(ax[u], bw[u], acc0);
            }
        }

        // slow poll (ground-truth rendezvous)
        for (long it = 0; it < (1L << 26); ++it) {
            int v = ldflag_l3(&flg[lane]);
            if (__ballot(v >= tgt) == ~0ull) break;
            __builtin_amdgcn_s_sleep(1);
        }
        __atomic_signal_fence(__ATOMIC_SEQ_CST);

        // fast-stamp visibility check (bounded; timeout = defect, not hang)
        {
            bool ok = false;
            for (long it = 0; it < 256; ++it) {
                int v = ldstamp(pollpF);
                if (__ballot(v >= tgtF) == ~0ull) { ok = true; break; }
                __builtin_amdgcn_s_sleep(1);
            }
            if (!ok) bad = 1;
        }

        if (L == 0) {
            if (t > 0) {
                const size_t offS = ((t - 1) & 3) * (64 * 512) + arow * 512 + q * 8;
                const size_t offF = ((t - 1) & DMASK) * (64 * 512) + arow * 512 + q * 8;
                half8 ah[16];
                #pragma unroll
                for (int u = 0; u < 16; ++u) {
                    ah[u] = ldfrag_l3(h0s + offS + u * 32);
                    half8 fh = ldfrag_fast(f0s + offF + u * 32);
                    bad |= neq8(ah[u], fh);
                }
                #pragma unroll
                for (int u = 0; u < 16; ++u) {
                    if (u & 1) acc1 = MFMA(ah[u], bw[16 + u], acc1);
                    else       acc0 = MFMA(ah[u], bw[16 + u], acc0);
                }
            }
        } else {
            {
                const size_t offS = (t & 3) * (64 * 512) + arow * 512 + q * 8;
                const size_t offF = (t & DMASK) * (64 * 512) + arow * 512 + q * 8;
                half8 ax[16];
                #pragma unroll
                for (int u = 0; u < 16; ++u) {
                    ax[u] = ldfrag_l3(h0s + offS + u * 32);
                    half8 fh = ldfrag_fast(f0s + offF + u * 32);
                    bad |= neq8(ax[u], fh);
                }
                #pragma unroll
                for (int u = 0; u < 16; ++u) {
                    if (u & 1) acc1 = MFMA(ax[u], bw[u], acc1);
                    else       acc0 = MFMA(ax[u], bw[u], acc0);
                }
            }
            if (t > 0) {
                const size_t offS = ((t - 1) & 3) * (64 * 512) + arow * 512 + q * 8;
                const size_t offF = ((t - 1) & DMASK) * (64 * 512) + arow * 512 + q * 8;
                half8 ah[16];
                #pragma unroll
                for (int u = 0; u < 16; ++u) {
                    ah[u] = ldfrag_l3(h1s + offS + u * 32);
                    half8 fh = ldfrag_fast(f1s + offF + u * 32);
                    bad |= neq8(ah[u], fh);
                }
                #pragma unroll
                for (int u = 0; u < 16; ++u) {
                    if (u & 1) acc1 = MFMA(ah[u], bw[16 + u], acc1);
                    else       acc0 = MFMA(ah[u], bw[16 + u], acc0);
                }
            }
        }

        float hv[4];
        #pragma unroll
        for (int r = 0; r < 4; ++r)
            hv[r] = tanhf(acc0[r] + acc1[r] + bias);

        {
            const size_t offS = (t & 3) * (64 * 512) + (size_t)(bg * 16) * 512 + col;
            const size_t offF = (t & DMASK) * (64 * 512) + (size_t)(bg * 16) * 512 + col;
            _Float16* hwS = ((L == 0) ? h0s : h1s) + offS;
            _Float16* hwF = ((L == 0) ? f0s : f1s) + offF;
            #pragma unroll
            for (int r = 0; r < 4; ++r) {
                union { _Float16 f; unsigned short u; } cv;
                cv.f = (_Float16)hv[r];
                st2_l3(hwS + (q * 4 + r) * 512, cv.u);
                hwF[(q * 4 + r) * 512] = cv.f;
            }
        }
        if (t == PROBE - 1) {
            const int anybad = (__ballot(bad) != 0ull) ? 1 : 0;
            if (lane == 0 && anybad)
                __hip_atomic_fetch_or(verdict, 1, __ATOMIC_RELAXED,
                                      __HIP_MEMORY_SCOPE_AGENT);
        }
        __atomic_signal_fence(__ATOMIC_SEQ_CST);
        __builtin_amdgcn_s_waitcnt(0);   // h (both mirrors) + verdict drained
        __atomic_signal_fence(__ATOMIC_SEQ_CST);
        if (lane == 0) ststamp(mystF, t + 1);
        __builtin_amdgcn_s_waitcnt(0);   // fast stamp ACKed before slow stamp
        if (lane == 0) stflag_l3(&flg[L * 32 + jg], t + 1);
    }
}

__global__ __launch_bounds__(128, 1)
void rnn_persist(const int* __restrict__ src, const float* __restrict__ embed,
                 const float* __restrict__ W_ih, const float* __restrict__ W_hh,
                 const float* __restrict__ b_ih, const float* __restrict__ b_hh,
                 float* __restrict__ out, _Float16* hS, _Float16* hF,
                 int* flagsS, int* flagsF, int* verdict, int fastEnable)
{
    const int b = blockIdx.x;
    if ((b & 7) >= 4) return;            // residues 4..7: padding blocks, exit
    const int bg  = b & 7;               // 0..3; XCD = b % 8 under round-robin
    const int jg  = b >> 3;
    const int tid = threadIdx.x;
    const int lane = tid & 63;
    const int L    = tid >> 6;           // wave0 = layer 0, wave1 = layer 1

    // persistent weights: 16 cols x K=1024, f16, 128 VGPRs
    const int q = lane >> 4, rr = lane & 15;
    const int col = jg * 16 + rr;
    half8 bw[32];
    {
        const float* Wi = W_ih + ((size_t)L * 512 + col) * 512;
        const float* Wh = W_hh + ((size_t)L * 512 + col) * 512;
        #pragma unroll
        for (int u = 0; u < 16; ++u) bw[u]      = cvt8(Wi + u * 32 + q * 8);
        #pragma unroll
        for (int u = 0; u < 16; ++u) bw[16 + u] = cvt8(Wh + u * 32 + q * 8);
    }
    const float bias = b_ih[L * 512 + col] + b_hh[L * 512 + col];

    _Float16* h0sS = hS;  _Float16* h1sS = hS + 4 * 64 * 512;
    _Float16* h0sF = hF;  _Float16* h1sF = hF + (size_t)DEPTH * 64 * 512;
    int* flgS = flagsS + bg * 64;
    int* flgF = flagsF + bg * 64 * FSTR;   // 8 KB of spread stamps per bg

    if (!fastEnable) {   // workspace too small: proven slow path only
        run_slow(0, lane, L, bg, jg, src, embed, bw, bias, out,
                 h0sS, h1sS, flgS);
        return;
    }

    run_probe(lane, L, bg, jg, src, embed, bw, bias,
              h0sS, h1sS, flgS, h0sF, h1sF, flgF, &verdict[bg]);

    // group barrier: all 64 stamps >= PROBE  =>  all verdict ORs are at MALL
    for (long it = 0; it < (1L << 26); ++it) {
        int v = ldflag_l3(&flgS[lane]);
        if (__ballot(v >= PROBE) == ~0ull) break;
        __builtin_amdgcn_s_sleep(1);
    }
    __atomic_signal_fence(__ATOMIC_SEQ_CST);
    const int vd = __hip_atomic_load(&verdict[bg], __ATOMIC_RELAXED,
                                     __HIP_MEMORY_SCOPE_AGENT);

    if (vd == 0) {
        run_fast(PROBE, lane, L, bg, jg, src, embed, bw, bias, out,
                 h0sF, h1sF, flgF);
    } else {
        // telemetry stall ~2 ms: a slow verdict is readable from dur_us
        for (int i = 0; i < 600; ++i) __builtin_amdgcn_s_sleep(125);
        run_slow(PROBE, lane, L, bg, jg, src, embed, bw, bias, out,
                 h0sS, h1sS, flgS);
    }
}

extern "C" void kernel_launch(void* const* d_in, const int* in_sizes, int n_in,
                              void* d_out, int out_size, void* d_ws, size_t ws_size,
                              hipStream_t stream) {
    const int*   src   = (const int*)  d_in[0];
    const float* embed = (const float*)d_in[1];
    const float* W_ih  = (const float*)d_in[2];
    const float* W_hh  = (const float*)d_in[3];
    const float* b_ih  = (const float*)d_in[4];
    const float* b_hh  = (const float*)d_in[5];
    float* out = (float*)d_out;

    int*      flagsS  = (int*)d_ws;                      // bytes [0,1024)
    int*      verdict = (int*)d_ws + 512;                // bytes [2048,2064)
    int*      flagsF  = (int*)((char*)d_ws + 32768);     // [32KB,64KB) spread
    _Float16* hS = (_Float16*)((char*)d_ws + 65536);     // 512 KB slow h
    // fast h: 2 layers x DEPTH(64) slots x 64x512 f16 = 8 MB at offset 1 MB
    const size_t need = (size_t)1048576
                      + (size_t)2 * DEPTH * 64 * 512 * 2 + 65536;
    const int fastEnable = (ws_size >= need) ? 1 : 0;
    _Float16* hF = fastEnable ? (_Float16*)((char*)d_ws + 1048576) : hS;

    // flags/verdict/fast stamps must start at 0 each launch (ws re-poisoned);
    // h slots need no init: t==0 skips all h-slot reads.
    hipMemsetAsync(d_ws, 0, 65536, stream);

    // 256 blocks x 128 threads; residues 0..3 (mod 8) active so each bg's 64
    // waves share one XCD. Co-residency by capacity: 256 blocks <= 256 CUs.
    rnn_persist<<<dim3(256), dim3(128), 0, stream>>>(
        src, embed, W_ih, W_hh, b_ih, b_hh, out, hS, hF,
        flagsS, flagsF, verdict, fastEnable);
}